// Round 16
// baseline (1704.511 us; speedup 1.0000x reference)
//
#include <hip/hip_runtime.h>
#include <math.h>

#define B_ 64
#define N_ 29
#define E_ 812
#define L_ 9
#define H_ 256
#define FA_ 5
#define BN_ (B_*N_)   // 1856
#define BE_ (B_*E_)   // 51968
#define DEG_ 28
#define NBAND_ (BN_/64)   // 29
#define SCALE_ 15.0f

typedef __attribute__((ext_vector_type(8))) short bf16x8;
typedef __attribute__((ext_vector_type(4))) float f32x4;

__device__ __forceinline__ float sigmoidf_(float v){ return 1.0f/(1.0f+expf(-v)); }
__device__ __forceinline__ float siluf_(float v){ return v/(1.0f+expf(-v)); }
// fast silu (edge path only): native exp + native rcp; ~5 ulp vs libm (proven safe R9)
__device__ __forceinline__ float fsilu_(float v){
    float e = __expf(-v);
    return v * __builtin_amdgcn_rcpf(1.0f + e);
}

// bf16 round-to-nearest-even conversion + back (exact RNE, proven path)
__device__ __forceinline__ ushort f2bf(float f){
    uint u = __float_as_uint(f);
    u += 0x7fffu + ((u>>16)&1u);
    return (ushort)(u>>16);
}
__device__ __forceinline__ float bf2f(ushort h){ return __uint_as_float(((uint)h)<<16); }

// ---------------- init ----------------
__global__ void k_init_h(const float* __restrict__ h_in, const float* __restrict__ t,
                         const float* __restrict__ win_w, const float* __restrict__ win_b,
                         float* __restrict__ h)
{
    int node = blockIdx.x; int c = threadIdx.x;
    float in[6];
    #pragma unroll
    for (int k=0;k<FA_;k++) in[k] = h_in[node*FA_+k];
    in[5] = t[node];
    float acc = win_b[c];
    #pragma unroll
    for (int k=0;k<6;k++) acc += in[k]*win_w[k*H_+c];
    h[(size_t)node*H_+c] = acc;
}

__global__ void k_init_xa(const float* __restrict__ x_in, const int* __restrict__ eidx,
                          const float* __restrict__ emask, float* __restrict__ x, float* __restrict__ a)
{
    int gid = blockIdx.x*256 + threadIdx.x;
    if (gid < BN_*3) x[gid] = x_in[gid];
    if (gid < BE_) {
        int b = gid / E_;
        int ii = eidx[2*gid], jj = eidx[2*gid+1];
        const float* xi = x_in + (size_t)(b*N_+ii)*3;
        const float* xj = x_in + (size_t)(b*N_+jj)*3;
        float dx = xi[0]-xj[0], dy = xi[1]-xj[1], dz = xi[2]-xj[2];
        a[gid] = sqrtf(dx*dx+dy*dy+dz*dz) * emask[gid];
    }
}

// ---------------- edge W fragmentization (bf16 hi/lo, 2 planes) ----------------
__global__ void k_wprep(const float* __restrict__ xw2, const float* __restrict__ ew2,
                        ushort* __restrict__ WfU, ushort* __restrict__ WfM)
{
    int gid = blockIdx.x*256 + threadIdx.x;
    if (gid >= L_*2*8192) return;
    int lane = gid & 63;
    int rest = gid >> 6;
    int ct = rest & 15; rest >>= 4;
    int ks = rest & 7;  rest >>= 3;
    int p  = rest & 1;  int l = rest >> 1;
    const float* src = (p ? ew2 : xw2) + (size_t)l*H_*H_;
    ushort* dst = (p ? WfM : WfU) + (size_t)l*131072;
    int g = lane>>4, li = lane&15;
    int col = ct*16 + li;
    int kb  = ks*32 + g*8;
    size_t fo = ((size_t)(ks*16+ct)*64 + lane)*8;
    ushort* dh = dst + fo;
    ushort* dl = dst + 65536 + fo;
    #pragma unroll
    for (int j=0;j<8;j++){
        float v = src[(size_t)(kb+j)*H_ + col];
        ushort h = f2bf(v);
        dh[j] = h;
        dl[j] = f2bf(v - bf2f(h));
    }
}

// ---------------- node W fragmentization for FEATURE batch (bf16 3-plane) ----------------
// 5 matrices per layer: m0 xw1_i, m1 xw1_j, m2 ew1_i, m3 ew1_j, m4 hw1_top.
__global__ void k_wprep6(const float* __restrict__ xw1, const float* __restrict__ ew1,
                         const float* __restrict__ hw1, ushort* __restrict__ Wf6)
{
    int gid = blockIdx.x*256 + threadIdx.x;
    if (gid >= L_*5*8192) return;
    int lane = gid & 63;
    int rest = gid >> 6;
    int ct = rest & 15; rest >>= 4;
    int ks = rest & 7;  rest >>= 3;
    int m  = rest % 5;  int l = rest / 5;
    const float* src;
    switch (m) {
        case 0: src = xw1 + (size_t)l*514*H_; break;
        case 1: src = xw1 + (size_t)l*514*H_ + (size_t)256*H_; break;
        case 2: src = ew1 + (size_t)l*514*H_; break;
        case 3: src = ew1 + (size_t)l*514*H_ + (size_t)256*H_; break;
        default: src = hw1 + (size_t)l*512*H_; break;
    }
    ushort* dst = Wf6 + (size_t)(l*5+m)*196608;
    int g = lane>>4, li = lane&15;
    int col = ct*16 + li;
    int kb  = ks*32 + g*8;
    size_t fo = ((size_t)(ks*16+ct)*64 + lane)*8;
    #pragma unroll
    for (int j=0;j<8;j++){
        float v = src[(size_t)(kb+j)*H_ + col];
        ushort h0 = f2bf(v); float r1 = v - bf2f(h0);
        ushort h1 = f2bf(r1); float r2 = r1 - bf2f(h1);
        dst[fo+j] = h0;
        dst[65536+fo+j] = h1;
        dst[131072+fo+j] = f2bf(r2);
    }
}

// ---------------- h -> 3-plane fragment conversion (coalesced; one octet per thread) ----------------
__global__ void k_hfrag(const float* __restrict__ h,
                        ushort* __restrict__ p0, ushort* __restrict__ p1, ushort* __restrict__ p2)
{
    int gid = blockIdx.x*256 + threadIdx.x;
    if (gid >= BN_*32) return;
    int row = gid >> 5, octet = gid & 31;
    const float* src = h + (size_t)row*H_ + octet*8;
    int band=row>>6, r=row&63, rt=r>>4, li=r&15;
    int ks=octet>>2, gg=octet&3;
    size_t fo = (((size_t)((band*8+ks)*4+rt)*64)+(gg*16+li))*8;
    ushort q0[8], q1[8], q2[8];
    #pragma unroll
    for (int j=0;j<8;j++){
        float v = src[j];
        ushort h0 = f2bf(v); float r1 = v - bf2f(h0);
        ushort h1 = f2bf(r1); float r2 = r1 - bf2f(h1);
        q0[j]=h0; q1[j]=h1; q2[j]=f2bf(r2);
    }
    *(ushort4*)(p0+fo)   = make_ushort4(q0[0],q0[1],q0[2],q0[3]);
    *(ushort4*)(p0+fo+4) = make_ushort4(q0[4],q0[5],q0[6],q0[7]);
    *(ushort4*)(p1+fo)   = make_ushort4(q1[0],q1[1],q1[2],q1[3]);
    *(ushort4*)(p1+fo+4) = make_ushort4(q1[4],q1[5],q1[6],q1[7]);
    *(ushort4*)(p2+fo)   = make_ushort4(q2[0],q2[1],q2[2],q2[3]);
    *(ushort4*)(p2+fo+4) = make_ushort4(q2[4],q2[5],q2[6],q2[7]);
}

// ---------------- generic tiled fp32 GEMM (h-chain: ha, h2) ----------------
struct GArg { const float* A; const float* Bw; const float* bias; const float* add; const float* rmask; float* C; };
struct GArgs { GArg g[6]; };

template<int ACT>
__global__ __launch_bounds__(256)
void k_gemm64(GArgs args, int M, int Kdim)
{
    const GArg ga = args.g[blockIdx.z];
    __shared__ float As[16*68];
    __shared__ float Bs[16*68];
    const int tid = threadIdx.x;
    const int row0 = blockIdx.x*64;
    const int col0 = blockIdx.y*64;
    const int ty = tid>>4, tx = tid&15;
    const int am = tid>>2, ak = (tid&3)<<2;
    const int bk = tid>>4, bn = (tid&15)<<2;
    float acc[4][4] = {};
    const float* Ap = ga.A + (size_t)min(row0+am, M-1)*Kdim + ak;
    const float* Bp = ga.Bw + (size_t)bk*H_ + col0 + bn;
    for (int k0=0; k0<Kdim; k0+=16) {
        float4 av = *(const float4*)(Ap + k0);
        float4 bv = *(const float4*)(Bp + (size_t)k0*H_);
        __syncthreads();
        As[(ak+0)*68+am]=av.x; As[(ak+1)*68+am]=av.y; As[(ak+2)*68+am]=av.z; As[(ak+3)*68+am]=av.w;
        *(float4*)&Bs[bk*68+bn] = bv;
        __syncthreads();
        #pragma unroll
        for (int k=0;k<16;k++) {
            float4 a4 = *(const float4*)&As[k*68 + (ty<<2)];
            float4 b4 = *(const float4*)&Bs[k*68 + (tx<<2)];
            float aa[4]={a4.x,a4.y,a4.z,a4.w};
            float bb[4]={b4.x,b4.y,b4.z,b4.w};
            #pragma unroll
            for (int i=0;i<4;i++)
                #pragma unroll
                for (int j=0;j<4;j++)
                    acc[i][j] = fmaf(aa[i], bb[j], acc[i][j]);
        }
    }
    const int r0 = row0 + (ty<<2);
    const int c0 = col0 + (tx<<2);
    float4 bias4 = make_float4(0.f,0.f,0.f,0.f);
    if (ga.bias) bias4 = *(const float4*)(ga.bias + c0);
    #pragma unroll
    for (int i=0;i<4;i++) {
        int r = r0+i;
        if (r >= M) break;
        float v0=acc[i][0]+bias4.x, v1=acc[i][1]+bias4.y, v2=acc[i][2]+bias4.z, v3=acc[i][3]+bias4.w;
        if (ga.add) {
            float4 ad = *(const float4*)(ga.add + (size_t)r*H_ + c0);
            v0+=ad.x; v1+=ad.y; v2+=ad.z; v3+=ad.w;
        }
        if (ACT==1) { v0=siluf_(v0); v1=siluf_(v1); v2=siluf_(v2); v3=siluf_(v3); }
        if (ga.rmask) { float mv = ga.rmask[r]; v0*=mv; v1*=mv; v2*=mv; v3*=mv; }
        *(float4*)(ga.C + (size_t)r*H_ + c0) = make_float4(v0,v1,v2,v3);
    }
}

// ---------------- feature GEMM via MFMA bf16x6: block = 64 rows x 64 cols ----------------
struct NArg6 { const ushort* A0; const ushort* A1; const ushort* A2;
               const ushort* Wf; float* Cf; };
struct NArgs6 { NArg6 g[5]; };

__global__ __launch_bounds__(256, 4)
void k_ngemm6(NArgs6 args)
{
    const NArg6 ga = args.g[blockIdx.z];
    const int tid  = threadIdx.x;
    const int lane = tid & 63;
    const int wv   = tid >> 6;
    const int g    = lane >> 4;
    const int li   = lane & 15;
    const int band = blockIdx.x;
    const int row0 = band*64;
    const int ctg  = blockIdx.y*4 + wv;   // global 16-col tile (0..15)

    const size_t abase = (size_t)band*16384 + (size_t)lane*8;    // + (ks*4+rt)*512
    const ushort* bp = ga.Wf + (size_t)ctg*512 + (size_t)lane*8; // + plane*65536 + ks*8192

    f32x4 acc[4];
    #pragma unroll
    for (int rt=0;rt<4;++rt) acc[rt] = (f32x4){0.f,0.f,0.f,0.f};

    #pragma unroll
    for (int ks=0; ks<8; ++ks){
        bf16x8 a0[4], a1[4], a2[4];
        #pragma unroll
        for (int rt=0; rt<4; ++rt){
            size_t o = abase + (size_t)(ks*4+rt)*512;
            a0[rt] = *(const bf16x8*)(ga.A0 + o);
            a1[rt] = *(const bf16x8*)(ga.A1 + o);
            a2[rt] = *(const bf16x8*)(ga.A2 + o);
        }
        bf16x8 b0 = *(const bf16x8*)(bp + ks*8192);
        bf16x8 b1 = *(const bf16x8*)(bp + 65536 + ks*8192);
        bf16x8 b2 = *(const bf16x8*)(bp + 131072 + ks*8192);
        #pragma unroll
        for (int rt=0; rt<4; ++rt){
            acc[rt] = __builtin_amdgcn_mfma_f32_16x16x32_bf16(a0[rt], b0, acc[rt], 0,0,0);
            acc[rt] = __builtin_amdgcn_mfma_f32_16x16x32_bf16(a1[rt], b0, acc[rt], 0,0,0);
            acc[rt] = __builtin_amdgcn_mfma_f32_16x16x32_bf16(a0[rt], b1, acc[rt], 0,0,0);
            acc[rt] = __builtin_amdgcn_mfma_f32_16x16x32_bf16(a1[rt], b1, acc[rt], 0,0,0);
            acc[rt] = __builtin_amdgcn_mfma_f32_16x16x32_bf16(a2[rt], b0, acc[rt], 0,0,0);
            acc[rt] = __builtin_amdgcn_mfma_f32_16x16x32_bf16(a0[rt], b2, acc[rt], 0,0,0);
        }
    }

    const int col = ctg*16 + li;
    #pragma unroll
    for (int rt=0; rt<4; ++rt){
        #pragma unroll
        for (int rg=0; rg<4; ++rg){
            int row = row0 + rt*16 + g*4 + rg;
            ga.Cf[(size_t)row*H_ + col] = acc[rt][rg];
        }
    }
}

// ---------------- half-K fragment compute (4 ks slices in LDS, 2 kq per thread) ----------------
// frag layout: [ksl(4)][rt(2)][lane(64)][8]. Wave wv: rt = wv&1, ksl base = (wv>>1)*2.
__device__ __forceinline__ void frag_half(
    const float* __restrict__ Xi, const float* __restrict__ Xj,
    const float* __restrict__ w5p, const float* __restrict__ w6p, const float* __restrict__ bp,
    int ni, int nj, float d2, float av, bool valid,
    int rt, int ksl0, int khalf, int lane,
    ushort (*fragH)[2][64][8], ushort (*fragL)[2][64][8])
{
    const int g = lane >> 4;
    if (valid){
        const float* xi = Xi + (size_t)ni*H_;
        const float* xj = Xj + (size_t)nj*H_;
        #pragma unroll
        for (int kq=0; kq<2; ++kq){
            int ksl = ksl0 + kq;
            int ks  = khalf*4 + ksl;
            int kb  = ks*32 + g*8;
            float4 i0 = *(const float4*)(xi + kb),  i1 = *(const float4*)(xi + kb + 4);
            float4 j0 = *(const float4*)(xj + kb),  j1 = *(const float4*)(xj + kb + 4);
            float4 w50= *(const float4*)(w5p + kb), w51= *(const float4*)(w5p + kb + 4);
            float4 w60= *(const float4*)(w6p + kb), w61= *(const float4*)(w6p + kb + 4);
            float4 b0 = *(const float4*)(bp + kb),  b1v= *(const float4*)(bp + kb + 4);
            float v[8];
            v[0]=fsilu_(i0.x+j0.x+d2*w50.x+av*w60.x+b0.x);
            v[1]=fsilu_(i0.y+j0.y+d2*w50.y+av*w60.y+b0.y);
            v[2]=fsilu_(i0.z+j0.z+d2*w50.z+av*w60.z+b0.z);
            v[3]=fsilu_(i0.w+j0.w+d2*w50.w+av*w60.w+b0.w);
            v[4]=fsilu_(i1.x+j1.x+d2*w51.x+av*w61.x+b1v.x);
            v[5]=fsilu_(i1.y+j1.y+d2*w51.y+av*w61.y+b1v.y);
            v[6]=fsilu_(i1.z+j1.z+d2*w51.z+av*w61.z+b1v.z);
            v[7]=fsilu_(i1.w+j1.w+d2*w51.w+av*w61.w+b1v.w);
            ushort hh[8], ll[8];
            #pragma unroll
            for (int q=0;q<8;q++){ hh[q]=f2bf(v[q]); ll[q]=f2bf(v[q]-bf2f(hh[q])); }
            *(ushort4*)&fragH[ksl][rt][lane][0] = make_ushort4(hh[0],hh[1],hh[2],hh[3]);
            *(ushort4*)&fragH[ksl][rt][lane][4] = make_ushort4(hh[4],hh[5],hh[6],hh[7]);
            *(ushort4*)&fragL[ksl][rt][lane][0] = make_ushort4(ll[0],ll[1],ll[2],ll[3]);
            *(ushort4*)&fragL[ksl][rt][lane][4] = make_ushort4(ll[4],ll[5],ll[6],ll[7]);
        }
    } else {
        ushort4 z4 = make_ushort4(0,0,0,0);
        #pragma unroll
        for (int kq=0; kq<2; ++kq){
            int ksl = ksl0 + kq;
            *(ushort4*)&fragH[ksl][rt][lane][0] = z4;
            *(ushort4*)&fragH[ksl][rt][lane][4] = z4;
            *(ushort4*)&fragL[ksl][rt][lane][0] = z4;
            *(ushort4*)&fragL[ksl][rt][lane][4] = z4;
        }
    }
}

// ---------------- half-K MFMA (4 local ks slices); acc chain identical to full-K ks ascending ----------------
__device__ __forceinline__ void mfma_half(
    const ushort (*fragH)[2][64][8], const ushort (*fragL)[2][64][8],
    const ushort* __restrict__ bp, int khalf, int lane, f32x4 (&acc)[2][4])
{
    #pragma unroll
    for (int ksl=0; ksl<4; ++ksl){
        const int ks = khalf*4 + ksl;
        bf16x8 ah[2], al[2];
        #pragma unroll
        for (int rt=0; rt<2; ++rt){
            ah[rt] = *(const bf16x8*)&fragH[ksl][rt][lane][0];
            al[rt] = *(const bf16x8*)&fragL[ksl][rt][lane][0];
        }
        #pragma unroll
        for (int ct=0; ct<4; ++ct){
            bf16x8 bh = *(const bf16x8*)(bp + ks*8192 + ct*512);
            bf16x8 bl = *(const bf16x8*)(bp + 65536 + ks*8192 + ct*512);
            #pragma unroll
            for (int rt=0; rt<2; ++rt){
                acc[rt][ct] = __builtin_amdgcn_mfma_f32_16x16x32_bf16(ah[rt], bh, acc[rt][ct], 0,0,0);
                acc[rt][ct] = __builtin_amdgcn_mfma_f32_16x16x32_bf16(al[rt], bh, acc[rt][ct], 0,0,0);
                acc[rt][ct] = __builtin_amdgcn_mfma_f32_16x16x32_bf16(ah[rt], bl, acc[rt][ct], 0,0,0);
            }
        }
    }
}

// ---------------- mega-fused edge kernel: one NODE per block, K split in halves (17.4 KB LDS, 8 blk/CU) ----------------
__global__ __launch_bounds__(256, 8)
void k_edge_mega(const float* __restrict__ XHi, const float* __restrict__ XHj,
                 const float* __restrict__ EHi, const float* __restrict__ EHj,
                 const float* __restrict__ x_cur, const float* __restrict__ a,
                 const int* __restrict__ eidx, const float* __restrict__ emask,
                 const float* __restrict__ nmask,
                 const float* __restrict__ xw512, const float* __restrict__ xw513, const float* __restrict__ xb1,
                 const float* __restrict__ ew512, const float* __restrict__ ew513, const float* __restrict__ eb1,
                 const ushort* __restrict__ WfU, const ushort* __restrict__ WfM,
                 const float* __restrict__ xb2, const float* __restrict__ xw3,
                 const float* __restrict__ eb2, const float* __restrict__ attw,
                 const float* __restrict__ attb,
                 float* __restrict__ x_new, float* __restrict__ agg)
{
    __shared__ __align__(16) ushort fragH[4][2][64][8];   // 8 KB
    __shared__ __align__(16) ushort fragL[4][2][64][8];   // 8 KB
    __shared__ float pdLds[2][4][32];                     // 1 KB
    __shared__ float easLds[32];
    __shared__ float cxyz[DEG_][3];

    const int tid  = threadIdx.x;
    const int lane = tid & 63;
    const int wv   = tid >> 6;
    const int g    = lane >> 4;
    const int li   = lane & 15;
    const int rt   = wv & 1;
    const int ksl0 = (wv >> 1)*2;
    const int n0   = blockIdx.x;

    const int frow = rt*16 + li;
    const bool valid = (frow < DEG_);
    int nj=0; float d2=0.f, av=0.f;
    if (valid){
        int bb = n0 / N_;
        size_t ge = (size_t)n0*DEG_ + frow;
        int jj = eidx[2*ge+1];
        nj = bb*N_ + jj;
        float em = emask[ge];
        float dx=(x_cur[n0*3+0]-x_cur[nj*3+0])*em;
        float dy=(x_cur[n0*3+1]-x_cur[nj*3+1])*em;
        float dz=(x_cur[n0*3+2]-x_cur[nj*3+2])*em;
        d2 = dx*dx+dy*dy+dz*dz;
        av = a[ge];
    }

    const ushort* bpU = WfU + ((size_t)(wv*4)*64 + lane)*8;
    const ushort* bpM = WfM + ((size_t)(wv*4)*64 + lane)*8;

    f32x4 acc[2][4];

    // ===== U pass (K halves) =====
    #pragma unroll
    for (int r=0;r<2;++r)
        #pragma unroll
        for (int ct=0;ct<4;++ct)
            acc[r][ct] = (f32x4){0.f,0.f,0.f,0.f};
    #pragma unroll
    for (int kh=0; kh<2; ++kh){
        frag_half(XHi, XHj, xw512, xw513, xb1, n0, nj, d2, av, valid, rt, ksl0, kh, lane, fragH, fragL);
        __syncthreads();
        mfma_half(fragH, fragL, bpU, kh, lane, acc);
        __syncthreads();
    }
    {
        float pdv[2][4];
        #pragma unroll
        for (int r=0;r<2;++r)
            #pragma unroll
            for (int rg=0;rg<4;++rg) pdv[r][rg]=0.f;
        #pragma unroll
        for (int ct=0; ct<4; ++ct){
            const int col = wv*64 + ct*16 + li;
            const float bi = xb2[col];
            const float wvv = xw3[col];
            #pragma unroll
            for (int r=0; r<2; ++r)
                #pragma unroll
                for (int rg=0; rg<4; ++rg)
                    pdv[r][rg] += fsilu_(acc[r][ct][rg] + bi)*wvv;
        }
        #pragma unroll
        for (int r=0;r<2;++r)
            #pragma unroll
            for (int rg=0;rg<4;++rg){
                float s = pdv[r][rg];
                s += __shfl_xor(s, 1, 16);
                s += __shfl_xor(s, 2, 16);
                s += __shfl_xor(s, 4, 16);
                s += __shfl_xor(s, 8, 16);
                if (li==0) pdLds[0][wv][r*16 + g*4 + rg] = s;
            }
    }
    __syncthreads();

    // ===== M pass (K halves) =====
    #pragma unroll
    for (int r=0;r<2;++r)
        #pragma unroll
        for (int ct=0;ct<4;++ct)
            acc[r][ct] = (f32x4){0.f,0.f,0.f,0.f};
    #pragma unroll
    for (int kh=0; kh<2; ++kh){
        frag_half(EHi, EHj, ew512, ew513, eb1, n0, nj, d2, av, valid, rt, ksl0, kh, lane, fragH, fragL);
        __syncthreads();
        mfma_half(fragH, fragL, bpM, kh, lane, acc);
        __syncthreads();
    }
    {
        float pdv[2][4];
        #pragma unroll
        for (int r=0;r<2;++r)
            #pragma unroll
            for (int rg=0;rg<4;++rg) pdv[r][rg]=0.f;
        #pragma unroll
        for (int ct=0; ct<4; ++ct){
            const int col = wv*64 + ct*16 + li;
            const float bi = eb2[col];
            const float wvv = attw[col];
            #pragma unroll
            for (int r=0; r<2; ++r)
                #pragma unroll
                for (int rg=0; rg<4; ++rg){
                    float v = fsilu_(acc[r][ct][rg] + bi);
                    acc[r][ct][rg] = v;
                    pdv[r][rg] += v*wvv;
                }
        }
        #pragma unroll
        for (int r=0;r<2;++r)
            #pragma unroll
            for (int rg=0;rg<4;++rg){
                float s = pdv[r][rg];
                s += __shfl_xor(s, 1, 16);
                s += __shfl_xor(s, 2, 16);
                s += __shfl_xor(s, 4, 16);
                s += __shfl_xor(s, 8, 16);
                if (li==0) pdLds[1][wv][r*16 + g*4 + rg] = s;
            }
    }
    __syncthreads();

    // ===== per-edge scalars + x update (wave 0) =====
    if (wv == 0){
        int t = lane;
        if (t < 32){
            float ea = 0.f;
            if (t < DEG_){
                float sU = pdLds[0][0][t]+pdLds[0][1][t]+pdLds[0][2][t]+pdLds[0][3][t];
                float sM = pdLds[1][0][t]+pdLds[1][1][t]+pdLds[1][2][t]+pdLds[1][3][t];
                float tsc = tanhf(sU)*SCALE_;
                ea = sigmoidf_(sM + attb[0]);
                size_t ge = (size_t)n0*DEG_ + t;
                int bb = n0 / N_;
                int jj = eidx[2*ge+1];
                int njs = bb*N_ + jj;
                float em = emask[ge];
                float dx=(x_cur[n0*3+0]-x_cur[njs*3+0])*em;
                float dy=(x_cur[n0*3+1]-x_cur[njs*3+1])*em;
                float dz=(x_cur[n0*3+2]-x_cur[njs*3+2])*em;
                float dd = sqrtf(dx*dx+dy*dy+dz*dz);
                float sc = tsc/(dd+1.0f);
                cxyz[t][0]=sc*dx; cxyz[t][1]=sc*dy; cxyz[t][2]=sc*dz;
            }
            easLds[t] = ea;
        }
        if (t == 0){
            float sx=0.f, sy=0.f, sz=0.f;
            #pragma unroll 4
            for (int k=0;k<DEG_;k++){ sx+=cxyz[k][0]; sy+=cxyz[k][1]; sz+=cxyz[k][2]; }
            float nm = nmask[n0];
            x_new[n0*3+0]=(x_cur[n0*3+0]+sx)*nm;
            x_new[n0*3+1]=(x_cur[n0*3+1]+sy)*nm;
            x_new[n0*3+2]=(x_cur[n0*3+2]+sz)*nm;
        }
    }
    __syncthreads();

    // ===== agg from register-resident M2 =====
    float p[4] = {0.f,0.f,0.f,0.f};
    #pragma unroll
    for (int r=0; r<2; ++r){
        #pragma unroll
        for (int rg=0; rg<4; ++rg){
            int row = r*16 + g*4 + rg;
            float w = easLds[row];
            #pragma unroll
            for (int ct=0; ct<4; ++ct)
                p[ct] += w*acc[r][ct][rg];
        }
    }
    #pragma unroll
    for (int ct=0; ct<4; ++ct){
        p[ct] += __shfl_xor(p[ct], 16);
        p[ct] += __shfl_xor(p[ct], 32);
    }
    if (g == 0){
        #pragma unroll
        for (int ct=0; ct<4; ++ct){
            int col = wv*64 + ct*16 + li;
            agg[(size_t)n0*H_ + col] = p[ct];
        }
    }
}

// ---------------- outputs ----------------
__global__ void k_out_x(const float* __restrict__ x, const float* __restrict__ x_in,
                        const float* __restrict__ nmask, float* __restrict__ out)
{
    int b = blockIdx.x; int l = threadIdx.x;
    int row = b*N_ + l;
    float xd0=0.f,xd1=0.f,xd2=0.f,nm=0.f;
    if (l < N_) {
        nm = nmask[row];
        xd0 = (x[(size_t)row*3+0]-x_in[(size_t)row*3+0])*nm;
        xd1 = (x[(size_t)row*3+1]-x_in[(size_t)row*3+1])*nm;
        xd2 = (x[(size_t)row*3+2]-x_in[(size_t)row*3+2])*nm;
    }
    float s0=xd0,s1=xd1,s2=xd2,sn=nm;
    #pragma unroll
    for (int off=32; off; off>>=1) {
        s0+=__shfl_xor(s0,off,64); s1+=__shfl_xor(s1,off,64);
        s2+=__shfl_xor(s2,off,64); sn+=__shfl_xor(sn,off,64);
    }
    float m0=s0/sn, m1=s1/sn, m2=s2/sn;
    if (l < N_) {
        out[(size_t)row*8+0]=(xd0-m0)*nm;
        out[(size_t)row*8+1]=(xd1-m1)*nm;
        out[(size_t)row*8+2]=(xd2-m2)*nm;
    }
}

__global__ void k_out_h(const float* __restrict__ h, const float* __restrict__ wout_w, const float* __restrict__ wout_b,
                        const float* __restrict__ nmask, float* __restrict__ out)
{
    int row = blockIdx.x; int lane = threadIdx.x;
    int c4 = lane<<2;
    float4 hv = *(const float4*)(h + (size_t)row*H_ + c4);
    float p0=0,p1=0,p2=0,p3=0,p4=0;
    float hvv[4] = {hv.x,hv.y,hv.z,hv.w};
    #pragma unroll
    for (int j=0;j<4;j++) {
        int k = c4+j;
        float hval = hvv[j];
        p0 += hval * wout_w[k*6+0];
        p1 += hval * wout_w[k*6+1];
        p2 += hval * wout_w[k*6+2];
        p3 += hval * wout_w[k*6+3];
        p4 += hval * wout_w[k*6+4];
    }
    #pragma unroll
    for (int off=32; off; off>>=1) {
        p0+=__shfl_xor(p0,off,64); p1+=__shfl_xor(p1,off,64); p2+=__shfl_xor(p2,off,64);
        p3+=__shfl_xor(p3,off,64); p4+=__shfl_xor(p4,off,64);
    }
    if (lane==0) {
        float nm = nmask[row];
        out[(size_t)row*8+3] = (p0+wout_b[0])*nm;
        out[(size_t)row*8+4] = (p1+wout_b[1])*nm;
        out[(size_t)row*8+5] = (p2+wout_b[2])*nm;
        out[(size_t)row*8+6] = (p3+wout_b[3])*nm;
        out[(size_t)row*8+7] = (p4+wout_b[4])*nm;
    }
}

extern "C" void kernel_launch(void* const* d_in, const int* in_sizes, int n_in,
                              void* d_out, int out_size, void* d_ws, size_t ws_size,
                              hipStream_t stream)
{
    const float* x_in  = (const float*)d_in[0];
    const float* h_in  = (const float*)d_in[1];
    const float* t     = (const float*)d_in[2];
    const float* nmask = (const float*)d_in[3];
    const float* emask = (const float*)d_in[4];
    const int*   eidx  = (const int*)d_in[5];
    const float* win_w = (const float*)d_in[6];
    const float* win_b = (const float*)d_in[7];
    const float* wout_w= (const float*)d_in[8];
    const float* wout_b= (const float*)d_in[9];
    const float* e_w1  = (const float*)d_in[10];
    const float* e_b1  = (const float*)d_in[11];
    const float* e_w2  = (const float*)d_in[12];
    const float* e_b2  = (const float*)d_in[13];
    const float* att_w = (const float*)d_in[14];
    const float* att_b = (const float*)d_in[15];
    const float* h_w1  = (const float*)d_in[16];
    const float* h_b1  = (const float*)d_in[17];
    const float* h_w2  = (const float*)d_in[18];
    const float* h_b2  = (const float*)d_in[19];
    const float* x_w1  = (const float*)d_in[20];
    const float* x_b1  = (const float*)d_in[21];
    const float* x_w2  = (const float*)d_in[22];
    const float* x_b2  = (const float*)d_in[23];
    const float* x_w3  = (const float*)d_in[24];
    float* out = (float*)d_out;

    char* ws = (char*)d_ws;
    size_t off = 0;
    auto alloc = [&](size_t bytes)->float* {
        float* p = (float*)(ws + off);
        off = (off + bytes + 255) & ~(size_t)255;
        return p;
    };
    const size_t PLANE = (size_t)NBAND_*16384;   // ushorts per A-plane
    float*  h     = alloc((size_t)BN_*H_*4);
    ushort* hp0   = (ushort*)alloc(PLANE*2);
    ushort* hp1   = (ushort*)alloc(PLANE*2);
    ushort* hp2   = (ushort*)alloc(PLANE*2);
    float*  xA    = alloc((size_t)BN_*3*4);
    float*  xB    = alloc((size_t)BN_*3*4);
    float*  a     = alloc((size_t)BE_*4);
    float*  NB5   = alloc((size_t)5*BN_*H_*4);
    float*  agg   = alloc((size_t)BN_*H_*4);
    float*  hm1   = alloc((size_t)BN_*H_*4);
    ushort* WfU   = (ushort*)alloc((size_t)L_*131072*sizeof(ushort));
    ushort* WfM   = (ushort*)alloc((size_t)L_*131072*sizeof(ushort));
    ushort* Wf6   = (ushort*)alloc((size_t)L_*5*196608*sizeof(ushort));

    k_init_h<<<BN_, H_, 0, stream>>>(h_in, t, win_w, win_b, h);
    k_init_xa<<<(BE_+255)/256, 256, 0, stream>>>(x_in, eidx, emask, xA, a);
    k_wprep<<<(L_*2*8192+255)/256, 256, 0, stream>>>(x_w2, e_w2, WfU, WfM);
    k_wprep6<<<(L_*5*8192+255)/256, 256, 0, stream>>>(x_w1, e_w1, h_w1, Wf6);

    float* x_cur = xA;
    float* x_new = xB;

    for (int l=0; l<L_; l++) {
        const float* xw1l = x_w1 + (size_t)l*514*H_;
        const float* ew1l = e_w1 + (size_t)l*514*H_;
        const float* hw1l = h_w1 + (size_t)l*512*H_;
        const ushort* Wl6 = Wf6 + (size_t)l*5*196608;

        float* XHi=NB5;
        float* XHj=NB5+(size_t)BN_*H_;
        float* EHi=NB5+(size_t)2*BN_*H_;
        float* EHj=NB5+(size_t)3*BN_*H_;
        float* Htop=NB5+(size_t)4*BN_*H_;

        // h -> 3-plane fragment order
        k_hfrag<<<(BN_*32+255)/256, 256, 0, stream>>>(h, hp0, hp1, hp2);

        // 5 feature GEMMs via bf16x6 MFMA, grid (29,4,5)
        NArgs6 na = {};
        for (int z=0; z<5; z++){
            na.g[z].A0=hp0; na.g[z].A1=hp1; na.g[z].A2=hp2;
            na.g[z].Wf = Wl6 + (size_t)z*196608;
            na.g[z].Cf = NB5 + (size_t)z*BN_*H_;
        }
        k_ngemm6<<<dim3(NBAND_,4,5),256,0,stream>>>(na);

        // mega-fused edge pipeline (K-split, 8 blocks/CU)
        k_edge_mega<<<BN_, 256, 0, stream>>>(XHi, XHj, EHi, EHj, x_cur, a,
            eidx, emask, nmask,
            xw1l+(size_t)512*H_, xw1l+(size_t)513*H_, x_b1+(size_t)l*H_,
            ew1l+(size_t)512*H_, ew1l+(size_t)513*H_, e_b1+(size_t)l*H_,
            WfU + (size_t)l*131072, WfM + (size_t)l*131072,
            x_b2+(size_t)l*H_, x_w3+(size_t)l*H_,
            e_b2+(size_t)l*H_, att_w+(size_t)l*H_, att_b+l,
            x_new, agg);

        // hm1 = silu(agg @ hw1_bot + h_b1 + Htop)  (fp32)
        GArgs ha = {};
        ha.g[0] = { agg, hw1l+(size_t)256*H_, h_b1+(size_t)l*H_, Htop, nullptr, hm1 };
        k_gemm64<1><<<dim3(BN_/64,H_/64,1),256,0,stream>>>(ha, BN_, H_);

        // h = (hm1 @ hw2 + h_b2 + h) * nmask  (fp32)
        GArgs h2 = {};
        h2.g[0] = { hm1, h_w2+(size_t)l*H_*H_, h_b2+(size_t)l*H_, h, nmask, h };
        k_gemm64<0><<<dim3(BN_/64,H_/64,1),256,0,stream>>>(h2, BN_, H_);

        float* tmp = x_cur; x_cur = x_new; x_new = tmp;
    }

    k_out_x<<<B_,64,0,stream>>>(x_cur, x_in, nmask, out);
    k_out_h<<<BN_,64,0,stream>>>(h, wout_w, wout_b, nmask, out);
}

// Round 17
// 1153.568 us; speedup vs baseline: 1.4776x; 1.4776x over previous
//
#include <hip/hip_runtime.h>
#include <math.h>

#define B_ 64
#define N_ 29
#define E_ 812
#define L_ 9
#define H_ 256
#define FA_ 5
#define BN_ (B_*N_)   // 1856
#define BE_ (B_*E_)   // 51968
#define DEG_ 28
#define NBAND_ (BN_/64)   // 29
#define SCALE_ 15.0f

typedef __attribute__((ext_vector_type(8))) short bf16x8;
typedef __attribute__((ext_vector_type(4))) float f32x4;

__device__ __forceinline__ float sigmoidf_(float v){ return 1.0f/(1.0f+expf(-v)); }
__device__ __forceinline__ float siluf_(float v){ return v/(1.0f+expf(-v)); }
// fast silu (edge path only): native exp + native rcp; ~5 ulp vs libm (proven safe R9)
__device__ __forceinline__ float fsilu_(float v){
    float e = __expf(-v);
    return v * __builtin_amdgcn_rcpf(1.0f + e);
}

// bf16 round-to-nearest-even conversion + back (exact RNE, proven path)
__device__ __forceinline__ ushort f2bf(float f){
    uint u = __float_as_uint(f);
    u += 0x7fffu + ((u>>16)&1u);
    return (ushort)(u>>16);
}
__device__ __forceinline__ float bf2f(ushort h){ return __uint_as_float(((uint)h)<<16); }

// ---------------- init ----------------
__global__ void k_init_h(const float* __restrict__ h_in, const float* __restrict__ t,
                         const float* __restrict__ win_w, const float* __restrict__ win_b,
                         float* __restrict__ h)
{
    int node = blockIdx.x; int c = threadIdx.x;
    float in[6];
    #pragma unroll
    for (int k=0;k<FA_;k++) in[k] = h_in[node*FA_+k];
    in[5] = t[node];
    float acc = win_b[c];
    #pragma unroll
    for (int k=0;k<6;k++) acc += in[k]*win_w[k*H_+c];
    h[(size_t)node*H_+c] = acc;
}

__global__ void k_init_xa(const float* __restrict__ x_in, const int* __restrict__ eidx,
                          const float* __restrict__ emask, float* __restrict__ x, float* __restrict__ a)
{
    int gid = blockIdx.x*256 + threadIdx.x;
    if (gid < BN_*3) x[gid] = x_in[gid];
    if (gid < BE_) {
        int b = gid / E_;
        int ii = eidx[2*gid], jj = eidx[2*gid+1];
        const float* xi = x_in + (size_t)(b*N_+ii)*3;
        const float* xj = x_in + (size_t)(b*N_+jj)*3;
        float dx = xi[0]-xj[0], dy = xi[1]-xj[1], dz = xi[2]-xj[2];
        a[gid] = sqrtf(dx*dx+dy*dy+dz*dz) * emask[gid];
    }
}

// ---------------- edge W fragmentization (bf16 hi/lo, 2 planes) ----------------
__global__ void k_wprep(const float* __restrict__ xw2, const float* __restrict__ ew2,
                        ushort* __restrict__ WfU, ushort* __restrict__ WfM)
{
    int gid = blockIdx.x*256 + threadIdx.x;
    if (gid >= L_*2*8192) return;
    int lane = gid & 63;
    int rest = gid >> 6;
    int ct = rest & 15; rest >>= 4;
    int ks = rest & 7;  rest >>= 3;
    int p  = rest & 1;  int l = rest >> 1;
    const float* src = (p ? ew2 : xw2) + (size_t)l*H_*H_;
    ushort* dst = (p ? WfM : WfU) + (size_t)l*131072;
    int g = lane>>4, li = lane&15;
    int col = ct*16 + li;
    int kb  = ks*32 + g*8;
    size_t fo = ((size_t)(ks*16+ct)*64 + lane)*8;
    ushort* dh = dst + fo;
    ushort* dl = dst + 65536 + fo;
    #pragma unroll
    for (int j=0;j<8;j++){
        float v = src[(size_t)(kb+j)*H_ + col];
        ushort h = f2bf(v);
        dh[j] = h;
        dl[j] = f2bf(v - bf2f(h));
    }
}

// ---------------- node W fragmentization for FEATURE batch (bf16 3-plane) ----------------
// 5 matrices per layer: m0 xw1_i, m1 xw1_j, m2 ew1_i, m3 ew1_j, m4 hw1_top.
__global__ void k_wprep6(const float* __restrict__ xw1, const float* __restrict__ ew1,
                         const float* __restrict__ hw1, ushort* __restrict__ Wf6)
{
    int gid = blockIdx.x*256 + threadIdx.x;
    if (gid >= L_*5*8192) return;
    int lane = gid & 63;
    int rest = gid >> 6;
    int ct = rest & 15; rest >>= 4;
    int ks = rest & 7;  rest >>= 3;
    int m  = rest % 5;  int l = rest / 5;
    const float* src;
    switch (m) {
        case 0: src = xw1 + (size_t)l*514*H_; break;
        case 1: src = xw1 + (size_t)l*514*H_ + (size_t)256*H_; break;
        case 2: src = ew1 + (size_t)l*514*H_; break;
        case 3: src = ew1 + (size_t)l*514*H_ + (size_t)256*H_; break;
        default: src = hw1 + (size_t)l*512*H_; break;
    }
    ushort* dst = Wf6 + (size_t)(l*5+m)*196608;
    int g = lane>>4, li = lane&15;
    int col = ct*16 + li;
    int kb  = ks*32 + g*8;
    size_t fo = ((size_t)(ks*16+ct)*64 + lane)*8;
    #pragma unroll
    for (int j=0;j<8;j++){
        float v = src[(size_t)(kb+j)*H_ + col];
        ushort h0 = f2bf(v); float r1 = v - bf2f(h0);
        ushort h1 = f2bf(r1); float r2 = r1 - bf2f(h1);
        dst[fo+j] = h0;
        dst[65536+fo+j] = h1;
        dst[131072+fo+j] = f2bf(r2);
    }
}

// ---------------- h -> 3-plane fragment conversion (coalesced; one octet per thread) ----------------
// plane layout [band][ks(8)][rt(4)][lane(64)][8]; lane=(gg*16+li) holds A[row][k=ks*32+gg*8+j]
__global__ void k_hfrag(const float* __restrict__ h,
                        ushort* __restrict__ p0, ushort* __restrict__ p1, ushort* __restrict__ p2)
{
    int gid = blockIdx.x*256 + threadIdx.x;
    if (gid >= BN_*32) return;
    int row = gid >> 5, octet = gid & 31;
    const float* src = h + (size_t)row*H_ + octet*8;
    int band=row>>6, r=row&63, rt=r>>4, li=r&15;
    int ks=octet>>2, gg=octet&3;
    size_t fo = (((size_t)((band*8+ks)*4+rt)*64)+(gg*16+li))*8;
    ushort q0[8], q1[8], q2[8];
    #pragma unroll
    for (int j=0;j<8;j++){
        float v = src[j];
        ushort h0 = f2bf(v); float r1 = v - bf2f(h0);
        ushort h1 = f2bf(r1); float r2 = r1 - bf2f(h1);
        q0[j]=h0; q1[j]=h1; q2[j]=f2bf(r2);
    }
    *(ushort4*)(p0+fo)   = make_ushort4(q0[0],q0[1],q0[2],q0[3]);
    *(ushort4*)(p0+fo+4) = make_ushort4(q0[4],q0[5],q0[6],q0[7]);
    *(ushort4*)(p1+fo)   = make_ushort4(q1[0],q1[1],q1[2],q1[3]);
    *(ushort4*)(p1+fo+4) = make_ushort4(q1[4],q1[5],q1[6],q1[7]);
    *(ushort4*)(p2+fo)   = make_ushort4(q2[0],q2[1],q2[2],q2[3]);
    *(ushort4*)(p2+fo+4) = make_ushort4(q2[4],q2[5],q2[6],q2[7]);
}

// ---------------- generic tiled fp32 GEMM (h-chain: ha, h2) ----------------
struct GArg { const float* A; const float* Bw; const float* bias; const float* add; const float* rmask; float* C; };
struct GArgs { GArg g[6]; };

template<int ACT>
__global__ __launch_bounds__(256)
void k_gemm64(GArgs args, int M, int Kdim)
{
    const GArg ga = args.g[blockIdx.z];
    __shared__ float As[16*68];
    __shared__ float Bs[16*68];
    const int tid = threadIdx.x;
    const int row0 = blockIdx.x*64;
    const int col0 = blockIdx.y*64;
    const int ty = tid>>4, tx = tid&15;
    const int am = tid>>2, ak = (tid&3)<<2;
    const int bk = tid>>4, bn = (tid&15)<<2;
    float acc[4][4] = {};
    const float* Ap = ga.A + (size_t)min(row0+am, M-1)*Kdim + ak;
    const float* Bp = ga.Bw + (size_t)bk*H_ + col0 + bn;
    for (int k0=0; k0<Kdim; k0+=16) {
        float4 av = *(const float4*)(Ap + k0);
        float4 bv = *(const float4*)(Bp + (size_t)k0*H_);
        __syncthreads();
        As[(ak+0)*68+am]=av.x; As[(ak+1)*68+am]=av.y; As[(ak+2)*68+am]=av.z; As[(ak+3)*68+am]=av.w;
        *(float4*)&Bs[bk*68+bn] = bv;
        __syncthreads();
        #pragma unroll
        for (int k=0;k<16;k++) {
            float4 a4 = *(const float4*)&As[k*68 + (ty<<2)];
            float4 b4 = *(const float4*)&Bs[k*68 + (tx<<2)];
            float aa[4]={a4.x,a4.y,a4.z,a4.w};
            float bb[4]={b4.x,b4.y,b4.z,b4.w};
            #pragma unroll
            for (int i=0;i<4;i++)
                #pragma unroll
                for (int j=0;j<4;j++)
                    acc[i][j] = fmaf(aa[i], bb[j], acc[i][j]);
        }
    }
    const int r0 = row0 + (ty<<2);
    const int c0 = col0 + (tx<<2);
    float4 bias4 = make_float4(0.f,0.f,0.f,0.f);
    if (ga.bias) bias4 = *(const float4*)(ga.bias + c0);
    #pragma unroll
    for (int i=0;i<4;i++) {
        int r = r0+i;
        if (r >= M) break;
        float v0=acc[i][0]+bias4.x, v1=acc[i][1]+bias4.y, v2=acc[i][2]+bias4.z, v3=acc[i][3]+bias4.w;
        if (ga.add) {
            float4 ad = *(const float4*)(ga.add + (size_t)r*H_ + c0);
            v0+=ad.x; v1+=ad.y; v2+=ad.z; v3+=ad.w;
        }
        if (ACT==1) { v0=siluf_(v0); v1=siluf_(v1); v2=siluf_(v2); v3=siluf_(v3); }
        if (ga.rmask) { float mv = ga.rmask[r]; v0*=mv; v1*=mv; v2*=mv; v3*=mv; }
        *(float4*)(ga.C + (size_t)r*H_ + c0) = make_float4(v0,v1,v2,v3);
    }
}

// ---------------- feature GEMM via MFMA bf16x6: block = 64 rows x 64 cols, wave = one 16-col tile ----------------
// Grid (NBAND_, 4, z=5) = 580 blocks. fp32 coalesced output only (no scatter epilogue).
struct NArg6 { const ushort* A0; const ushort* A1; const ushort* A2;
               const ushort* Wf; float* Cf; };
struct NArgs6 { NArg6 g[5]; };

__global__ __launch_bounds__(256, 4)
void k_ngemm6(NArgs6 args)
{
    const NArg6 ga = args.g[blockIdx.z];
    const int tid  = threadIdx.x;
    const int lane = tid & 63;
    const int wv   = tid >> 6;
    const int g    = lane >> 4;
    const int li   = lane & 15;
    const int band = blockIdx.x;
    const int row0 = band*64;
    const int ctg  = blockIdx.y*4 + wv;   // global 16-col tile (0..15)

    const size_t abase = (size_t)band*16384 + (size_t)lane*8;    // + (ks*4+rt)*512
    const ushort* bp = ga.Wf + (size_t)ctg*512 + (size_t)lane*8; // + plane*65536 + ks*8192

    f32x4 acc[4];
    #pragma unroll
    for (int rt=0;rt<4;++rt) acc[rt] = (f32x4){0.f,0.f,0.f,0.f};

    #pragma unroll
    for (int ks=0; ks<8; ++ks){
        bf16x8 a0[4], a1[4], a2[4];
        #pragma unroll
        for (int rt=0; rt<4; ++rt){
            size_t o = abase + (size_t)(ks*4+rt)*512;
            a0[rt] = *(const bf16x8*)(ga.A0 + o);
            a1[rt] = *(const bf16x8*)(ga.A1 + o);
            a2[rt] = *(const bf16x8*)(ga.A2 + o);
        }
        bf16x8 b0 = *(const bf16x8*)(bp + ks*8192);
        bf16x8 b1 = *(const bf16x8*)(bp + 65536 + ks*8192);
        bf16x8 b2 = *(const bf16x8*)(bp + 131072 + ks*8192);
        #pragma unroll
        for (int rt=0; rt<4; ++rt){
            acc[rt] = __builtin_amdgcn_mfma_f32_16x16x32_bf16(a0[rt], b0, acc[rt], 0,0,0);
            acc[rt] = __builtin_amdgcn_mfma_f32_16x16x32_bf16(a1[rt], b0, acc[rt], 0,0,0);
            acc[rt] = __builtin_amdgcn_mfma_f32_16x16x32_bf16(a0[rt], b1, acc[rt], 0,0,0);
            acc[rt] = __builtin_amdgcn_mfma_f32_16x16x32_bf16(a1[rt], b1, acc[rt], 0,0,0);
            acc[rt] = __builtin_amdgcn_mfma_f32_16x16x32_bf16(a2[rt], b0, acc[rt], 0,0,0);
            acc[rt] = __builtin_amdgcn_mfma_f32_16x16x32_bf16(a0[rt], b2, acc[rt], 0,0,0);
        }
    }

    const int col = ctg*16 + li;
    #pragma unroll
    for (int rt=0; rt<4; ++rt){
        #pragma unroll
        for (int rg=0; rg<4; ++rg){
            int row = row0 + rt*16 + g*4 + rg;
            ga.Cf[(size_t)row*H_ + col] = acc[rt][rg];
        }
    }
}

// ---------------- in-LDS fragment compute (32-row band, one pass, 4 ks per thread) ----------------
__device__ __forceinline__ void frag_compute(
    const float* __restrict__ Xi, const float* __restrict__ Xj,
    const float* __restrict__ w5p, const float* __restrict__ w6p, const float* __restrict__ bp,
    int ni, int nj, float d2, float av, bool valid,
    int rt, int ks0, int lane,
    ushort (*fragH)[2][64][8], ushort (*fragL)[2][64][8])
{
    const int g = lane >> 4;
    if (valid){
        const float* xi = Xi + (size_t)ni*H_;
        const float* xj = Xj + (size_t)nj*H_;
        #pragma unroll
        for (int kq=0; kq<4; ++kq){
            int ks = ks0 + kq;
            int kb = ks*32 + g*8;
            float4 i0 = *(const float4*)(xi + kb),  i1 = *(const float4*)(xi + kb + 4);
            float4 j0 = *(const float4*)(xj + kb),  j1 = *(const float4*)(xj + kb + 4);
            float4 w50= *(const float4*)(w5p + kb), w51= *(const float4*)(w5p + kb + 4);
            float4 w60= *(const float4*)(w6p + kb), w61= *(const float4*)(w6p + kb + 4);
            float4 b0 = *(const float4*)(bp + kb),  b1v= *(const float4*)(bp + kb + 4);
            float v[8];
            v[0]=fsilu_(i0.x+j0.x+d2*w50.x+av*w60.x+b0.x);
            v[1]=fsilu_(i0.y+j0.y+d2*w50.y+av*w60.y+b0.y);
            v[2]=fsilu_(i0.z+j0.z+d2*w50.z+av*w60.z+b0.z);
            v[3]=fsilu_(i0.w+j0.w+d2*w50.w+av*w60.w+b0.w);
            v[4]=fsilu_(i1.x+j1.x+d2*w51.x+av*w61.x+b1v.x);
            v[5]=fsilu_(i1.y+j1.y+d2*w51.y+av*w61.y+b1v.y);
            v[6]=fsilu_(i1.z+j1.z+d2*w51.z+av*w61.z+b1v.z);
            v[7]=fsilu_(i1.w+j1.w+d2*w51.w+av*w61.w+b1v.w);
            ushort hh[8], ll[8];
            #pragma unroll
            for (int q=0;q<8;q++){ hh[q]=f2bf(v[q]); ll[q]=f2bf(v[q]-bf2f(hh[q])); }
            *(ushort4*)&fragH[ks][rt][lane][0] = make_ushort4(hh[0],hh[1],hh[2],hh[3]);
            *(ushort4*)&fragH[ks][rt][lane][4] = make_ushort4(hh[4],hh[5],hh[6],hh[7]);
            *(ushort4*)&fragL[ks][rt][lane][0] = make_ushort4(ll[0],ll[1],ll[2],ll[3]);
            *(ushort4*)&fragL[ks][rt][lane][4] = make_ushort4(ll[4],ll[5],ll[6],ll[7]);
        }
    } else {
        ushort4 z4 = make_ushort4(0,0,0,0);
        #pragma unroll
        for (int kq=0; kq<4; ++kq){
            int ks = ks0 + kq;
            *(ushort4*)&fragH[ks][rt][lane][0] = z4;
            *(ushort4*)&fragH[ks][rt][lane][4] = z4;
            *(ushort4*)&fragL[ks][rt][lane][0] = z4;
            *(ushort4*)&fragL[ks][rt][lane][4] = z4;
        }
    }
}

// ---------------- MFMA mainloop, B-stream pipelined 1 ks deep ----------------
__device__ __forceinline__ void mfma_lds(
    const ushort (*fragH)[2][64][8], const ushort (*fragL)[2][64][8],
    const ushort* __restrict__ bp, int lane, f32x4 (&acc)[2][4])
{
    bf16x8 bh[2][4], bl[2][4];
    #pragma unroll
    for (int ct=0; ct<4; ++ct){
        bh[0][ct] = *(const bf16x8*)(bp + ct*512);
        bl[0][ct] = *(const bf16x8*)(bp + 65536 + ct*512);
    }
    #pragma unroll
    for (int ks=0; ks<8; ++ks){
        const int cur = ks & 1;
        const int nxt = cur ^ 1;
        if (ks < 7){
            #pragma unroll
            for (int ct=0; ct<4; ++ct){
                bh[nxt][ct] = *(const bf16x8*)(bp + (ks+1)*8192 + ct*512);
                bl[nxt][ct] = *(const bf16x8*)(bp + 65536 + (ks+1)*8192 + ct*512);
            }
        }
        bf16x8 ah[2], al[2];
        #pragma unroll
        for (int rt=0; rt<2; ++rt){
            ah[rt] = *(const bf16x8*)&fragH[ks][rt][lane][0];
            al[rt] = *(const bf16x8*)&fragL[ks][rt][lane][0];
        }
        #pragma unroll
        for (int ct=0; ct<4; ++ct){
            #pragma unroll
            for (int rt=0; rt<2; ++rt){
                acc[rt][ct] = __builtin_amdgcn_mfma_f32_16x16x32_bf16(ah[rt], bh[cur][ct], acc[rt][ct], 0,0,0);
                acc[rt][ct] = __builtin_amdgcn_mfma_f32_16x16x32_bf16(al[rt], bh[cur][ct], acc[rt][ct], 0,0,0);
                acc[rt][ct] = __builtin_amdgcn_mfma_f32_16x16x32_bf16(ah[rt], bl[cur][ct], acc[rt][ct], 0,0,0);
            }
        }
    }
}

// ---------------- mega-fused edge kernel: one NODE per block (28 edges padded to 32 rows) ----------------
__global__ __launch_bounds__(256, 4)
void k_edge_mega(const float* __restrict__ XHi, const float* __restrict__ XHj,
                 const float* __restrict__ EHi, const float* __restrict__ EHj,
                 const float* __restrict__ x_cur, const float* __restrict__ a,
                 const int* __restrict__ eidx, const float* __restrict__ emask,
                 const float* __restrict__ nmask,
                 const float* __restrict__ xw512, const float* __restrict__ xw513, const float* __restrict__ xb1,
                 const float* __restrict__ ew512, const float* __restrict__ ew513, const float* __restrict__ eb1,
                 const ushort* __restrict__ WfU, const ushort* __restrict__ WfM,
                 const float* __restrict__ xb2, const float* __restrict__ xw3,
                 const float* __restrict__ eb2, const float* __restrict__ attw,
                 const float* __restrict__ attb,
                 float* __restrict__ x_new, float* __restrict__ agg)
{
    __shared__ __align__(16) ushort fragH[8][2][64][8];   // 16 KB
    __shared__ __align__(16) ushort fragL[8][2][64][8];   // 16 KB
    __shared__ float pdLds[2][4][32];                     // 1 KB
    __shared__ float easLds[32];
    __shared__ float cxyz[DEG_][3];

    const int tid  = threadIdx.x;
    const int lane = tid & 63;
    const int wv   = tid >> 6;
    const int g    = lane >> 4;
    const int li   = lane & 15;
    const int rt   = wv & 1;
    const int ks0  = (wv >> 1)*4;
    const int n0   = blockIdx.x;

    const int frow = rt*16 + li;
    const bool valid = (frow < DEG_);
    int nj=0; float d2=0.f, av=0.f;
    if (valid){
        int bb = n0 / N_;
        size_t ge = (size_t)n0*DEG_ + frow;
        int jj = eidx[2*ge+1];
        nj = bb*N_ + jj;
        float em = emask[ge];
        float dx=(x_cur[n0*3+0]-x_cur[nj*3+0])*em;
        float dy=(x_cur[n0*3+1]-x_cur[nj*3+1])*em;
        float dz=(x_cur[n0*3+2]-x_cur[nj*3+2])*em;
        d2 = dx*dx+dy*dy+dz*dz;
        av = a[ge];
    }

    const ushort* bpU = WfU + ((size_t)(wv*4)*64 + lane)*8;
    const ushort* bpM = WfM + ((size_t)(wv*4)*64 + lane)*8;

    f32x4 acc[2][4];

    // ===== phase 1: u1 fragments -> LDS =====
    frag_compute(XHi, XHj, xw512, xw513, xb1, n0, nj, d2, av, valid, rt, ks0, lane, fragH, fragL);
    __syncthreads();

    // ===== phase 2: U-pass GEMM + pd epilogue =====
    #pragma unroll
    for (int r=0;r<2;++r)
        #pragma unroll
        for (int ct=0;ct<4;++ct)
            acc[r][ct] = (f32x4){0.f,0.f,0.f,0.f};
    mfma_lds(fragH, fragL, bpU, lane, acc);
    {
        float pdv[2][4];
        #pragma unroll
        for (int r=0;r<2;++r)
            #pragma unroll
            for (int rg=0;rg<4;++rg) pdv[r][rg]=0.f;
        #pragma unroll
        for (int ct=0; ct<4; ++ct){
            const int col = wv*64 + ct*16 + li;
            const float bi = xb2[col];
            const float wvv = xw3[col];
            #pragma unroll
            for (int r=0; r<2; ++r)
                #pragma unroll
                for (int rg=0; rg<4; ++rg)
                    pdv[r][rg] += fsilu_(acc[r][ct][rg] + bi)*wvv;
        }
        #pragma unroll
        for (int r=0;r<2;++r)
            #pragma unroll
            for (int rg=0;rg<4;++rg){
                float s = pdv[r][rg];
                s += __shfl_xor(s, 1, 16);
                s += __shfl_xor(s, 2, 16);
                s += __shfl_xor(s, 4, 16);
                s += __shfl_xor(s, 8, 16);
                if (li==0) pdLds[0][wv][r*16 + g*4 + rg] = s;
            }
    }
    __syncthreads();

    // ===== phase 3: m1 fragments -> LDS (overwrite) =====
    frag_compute(EHi, EHj, ew512, ew513, eb1, n0, nj, d2, av, valid, rt, ks0, lane, fragH, fragL);
    __syncthreads();

    // ===== phase 4: M-pass GEMM + pd epilogue (M2 stays in regs) =====
    #pragma unroll
    for (int r=0;r<2;++r)
        #pragma unroll
        for (int ct=0;ct<4;++ct)
            acc[r][ct] = (f32x4){0.f,0.f,0.f,0.f};
    mfma_lds(fragH, fragL, bpM, lane, acc);
    {
        float pdv[2][4];
        #pragma unroll
        for (int r=0;r<2;++r)
            #pragma unroll
            for (int rg=0;rg<4;++rg) pdv[r][rg]=0.f;
        #pragma unroll
        for (int ct=0; ct<4; ++ct){
            const int col = wv*64 + ct*16 + li;
            const float bi = eb2[col];
            const float wvv = attw[col];
            #pragma unroll
            for (int r=0; r<2; ++r)
                #pragma unroll
                for (int rg=0; rg<4; ++rg){
                    float v = fsilu_(acc[r][ct][rg] + bi);
                    acc[r][ct][rg] = v;
                    pdv[r][rg] += v*wvv;
                }
        }
        #pragma unroll
        for (int r=0;r<2;++r)
            #pragma unroll
            for (int rg=0;rg<4;++rg){
                float s = pdv[r][rg];
                s += __shfl_xor(s, 1, 16);
                s += __shfl_xor(s, 2, 16);
                s += __shfl_xor(s, 4, 16);
                s += __shfl_xor(s, 8, 16);
                if (li==0) pdLds[1][wv][r*16 + g*4 + rg] = s;
            }
    }
    __syncthreads();

    // ===== phase 5: per-edge scalars + x update (wave 0) =====
    if (wv == 0){
        int t = lane;
        if (t < 32){
            float ea = 0.f;
            if (t < DEG_){
                float sU = pdLds[0][0][t]+pdLds[0][1][t]+pdLds[0][2][t]+pdLds[0][3][t];
                float sM = pdLds[1][0][t]+pdLds[1][1][t]+pdLds[1][2][t]+pdLds[1][3][t];
                float tsc = tanhf(sU)*SCALE_;
                ea = sigmoidf_(sM + attb[0]);
                size_t ge = (size_t)n0*DEG_ + t;
                int bb = n0 / N_;
                int jj = eidx[2*ge+1];
                int njs = bb*N_ + jj;
                float em = emask[ge];
                float dx=(x_cur[n0*3+0]-x_cur[njs*3+0])*em;
                float dy=(x_cur[n0*3+1]-x_cur[njs*3+1])*em;
                float dz=(x_cur[n0*3+2]-x_cur[njs*3+2])*em;
                float dd = sqrtf(dx*dx+dy*dy+dz*dz);
                float sc = tsc/(dd+1.0f);
                cxyz[t][0]=sc*dx; cxyz[t][1]=sc*dy; cxyz[t][2]=sc*dz;
            }
            easLds[t] = ea;
        }
        if (t == 0){
            float sx=0.f, sy=0.f, sz=0.f;
            #pragma unroll 4
            for (int k=0;k<DEG_;k++){ sx+=cxyz[k][0]; sy+=cxyz[k][1]; sz+=cxyz[k][2]; }
            float nm = nmask[n0];
            x_new[n0*3+0]=(x_cur[n0*3+0]+sx)*nm;
            x_new[n0*3+1]=(x_cur[n0*3+1]+sy)*nm;
            x_new[n0*3+2]=(x_cur[n0*3+2]+sz)*nm;
        }
    }
    __syncthreads();

    // ===== phase 6: agg from register-resident M2 =====
    float p[4] = {0.f,0.f,0.f,0.f};
    #pragma unroll
    for (int r=0; r<2; ++r){
        #pragma unroll
        for (int rg=0; rg<4; ++rg){
            int row = r*16 + g*4 + rg;
            float w = easLds[row];
            #pragma unroll
            for (int ct=0; ct<4; ++ct)
                p[ct] += w*acc[r][ct][rg];
        }
    }
    #pragma unroll
    for (int ct=0; ct<4; ++ct){
        p[ct] += __shfl_xor(p[ct], 16);
        p[ct] += __shfl_xor(p[ct], 32);
    }
    if (g == 0){
        #pragma unroll
        for (int ct=0; ct<4; ++ct){
            int col = wv*64 + ct*16 + li;
            agg[(size_t)n0*H_ + col] = p[ct];
        }
    }
}

// ---------------- outputs ----------------
__global__ void k_out_x(const float* __restrict__ x, const float* __restrict__ x_in,
                        const float* __restrict__ nmask, float* __restrict__ out)
{
    int b = blockIdx.x; int l = threadIdx.x;
    int row = b*N_ + l;
    float xd0=0.f,xd1=0.f,xd2=0.f,nm=0.f;
    if (l < N_) {
        nm = nmask[row];
        xd0 = (x[(size_t)row*3+0]-x_in[(size_t)row*3+0])*nm;
        xd1 = (x[(size_t)row*3+1]-x_in[(size_t)row*3+1])*nm;
        xd2 = (x[(size_t)row*3+2]-x_in[(size_t)row*3+2])*nm;
    }
    float s0=xd0,s1=xd1,s2=xd2,sn=nm;
    #pragma unroll
    for (int off=32; off; off>>=1) {
        s0+=__shfl_xor(s0,off,64); s1+=__shfl_xor(s1,off,64);
        s2+=__shfl_xor(s2,off,64); sn+=__shfl_xor(sn,off,64);
    }
    float m0=s0/sn, m1=s1/sn, m2=s2/sn;
    if (l < N_) {
        out[(size_t)row*8+0]=(xd0-m0)*nm;
        out[(size_t)row*8+1]=(xd1-m1)*nm;
        out[(size_t)row*8+2]=(xd2-m2)*nm;
    }
}

__global__ void k_out_h(const float* __restrict__ h, const float* __restrict__ wout_w, const float* __restrict__ wout_b,
                        const float* __restrict__ nmask, float* __restrict__ out)
{
    int row = blockIdx.x; int lane = threadIdx.x;
    int c4 = lane<<2;
    float4 hv = *(const float4*)(h + (size_t)row*H_ + c4);
    float p0=0,p1=0,p2=0,p3=0,p4=0;
    float hvv[4] = {hv.x,hv.y,hv.z,hv.w};
    #pragma unroll
    for (int j=0;j<4;j++) {
        int k = c4+j;
        float hval = hvv[j];
        p0 += hval * wout_w[k*6+0];
        p1 += hval * wout_w[k*6+1];
        p2 += hval * wout_w[k*6+2];
        p3 += hval * wout_w[k*6+3];
        p4 += hval * wout_w[k*6+4];
    }
    #pragma unroll
    for (int off=32; off; off>>=1) {
        p0+=__shfl_xor(p0,off,64); p1+=__shfl_xor(p1,off,64); p2+=__shfl_xor(p2,off,64);
        p3+=__shfl_xor(p3,off,64); p4+=__shfl_xor(p4,off,64);
    }
    if (lane==0) {
        float nm = nmask[row];
        out[(size_t)row*8+3] = (p0+wout_b[0])*nm;
        out[(size_t)row*8+4] = (p1+wout_b[1])*nm;
        out[(size_t)row*8+5] = (p2+wout_b[2])*nm;
        out[(size_t)row*8+6] = (p3+wout_b[3])*nm;
        out[(size_t)row*8+7] = (p4+wout_b[4])*nm;
    }
}

extern "C" void kernel_launch(void* const* d_in, const int* in_sizes, int n_in,
                              void* d_out, int out_size, void* d_ws, size_t ws_size,
                              hipStream_t stream)
{
    const float* x_in  = (const float*)d_in[0];
    const float* h_in  = (const float*)d_in[1];
    const float* t     = (const float*)d_in[2];
    const float* nmask = (const float*)d_in[3];
    const float* emask = (const float*)d_in[4];
    const int*   eidx  = (const int*)d_in[5];
    const float* win_w = (const float*)d_in[6];
    const float* win_b = (const float*)d_in[7];
    const float* wout_w= (const float*)d_in[8];
    const float* wout_b= (const float*)d_in[9];
    const float* e_w1  = (const float*)d_in[10];
    const float* e_b1  = (const float*)d_in[11];
    const float* e_w2  = (const float*)d_in[12];
    const float* e_b2  = (const float*)d_in[13];
    const float* att_w = (const float*)d_in[14];
    const float* att_b = (const float*)d_in[15];
    const float* h_w1  = (const float*)d_in[16];
    const float* h_b1  = (const float*)d_in[17];
    const float* h_w2  = (const float*)d_in[18];
    const float* h_b2  = (const float*)d_in[19];
    const float* x_w1  = (const float*)d_in[20];
    const float* x_b1  = (const float*)d_in[21];
    const float* x_w2  = (const float*)d_in[22];
    const float* x_b2  = (const float*)d_in[23];
    const float* x_w3  = (const float*)d_in[24];
    float* out = (float*)d_out;

    char* ws = (char*)d_ws;
    size_t off = 0;
    auto alloc = [&](size_t bytes)->float* {
        float* p = (float*)(ws + off);
        off = (off + bytes + 255) & ~(size_t)255;
        return p;
    };
    const size_t PLANE = (size_t)NBAND_*16384;   // ushorts per A-plane
    float*  h     = alloc((size_t)BN_*H_*4);
    ushort* hp0   = (ushort*)alloc(PLANE*2);
    ushort* hp1   = (ushort*)alloc(PLANE*2);
    ushort* hp2   = (ushort*)alloc(PLANE*2);
    float*  xA    = alloc((size_t)BN_*3*4);
    float*  xB    = alloc((size_t)BN_*3*4);
    float*  a     = alloc((size_t)BE_*4);
    float*  NB5   = alloc((size_t)5*BN_*H_*4);
    float*  agg   = alloc((size_t)BN_*H_*4);
    float*  hm1   = alloc((size_t)BN_*H_*4);
    ushort* WfU   = (ushort*)alloc((size_t)L_*131072*sizeof(ushort));
    ushort* WfM   = (ushort*)alloc((size_t)L_*131072*sizeof(ushort));
    ushort* Wf6   = (ushort*)alloc((size_t)L_*5*196608*sizeof(ushort));

    k_init_h<<<BN_, H_, 0, stream>>>(h_in, t, win_w, win_b, h);
    k_init_xa<<<(BE_+255)/256, 256, 0, stream>>>(x_in, eidx, emask, xA, a);
    k_wprep<<<(L_*2*8192+255)/256, 256, 0, stream>>>(x_w2, e_w2, WfU, WfM);
    k_wprep6<<<(L_*5*8192+255)/256, 256, 0, stream>>>(x_w1, e_w1, h_w1, Wf6);

    float* x_cur = xA;
    float* x_new = xB;

    for (int l=0; l<L_; l++) {
        const float* xw1l = x_w1 + (size_t)l*514*H_;
        const float* ew1l = e_w1 + (size_t)l*514*H_;
        const float* hw1l = h_w1 + (size_t)l*512*H_;
        const ushort* Wl6 = Wf6 + (size_t)l*5*196608;

        float* XHi=NB5;
        float* XHj=NB5+(size_t)BN_*H_;
        float* EHi=NB5+(size_t)2*BN_*H_;
        float* EHj=NB5+(size_t)3*BN_*H_;
        float* Htop=NB5+(size_t)4*BN_*H_;

        // h -> 3-plane fragment order (decouples h-chain from feature MFMA)
        k_hfrag<<<(BN_*32+255)/256, 256, 0, stream>>>(h, hp0, hp1, hp2);

        // 5 feature GEMMs (XHi,XHj,EHi,EHj,Htop) via bf16x6 MFMA, grid (29,4,5)
        NArgs6 na = {};
        for (int z=0; z<5; z++){
            na.g[z].A0=hp0; na.g[z].A1=hp1; na.g[z].A2=hp2;
            na.g[z].Wf = Wl6 + (size_t)z*196608;
            na.g[z].Cf = NB5 + (size_t)z*BN_*H_;
        }
        k_ngemm6<<<dim3(NBAND_,4,5),256,0,stream>>>(na);

        // mega-fused edge pipeline (R12 version, fp32 agg out)
        k_edge_mega<<<BN_, 256, 0, stream>>>(XHi, XHj, EHi, EHj, x_cur, a,
            eidx, emask, nmask,
            xw1l+(size_t)512*H_, xw1l+(size_t)513*H_, x_b1+(size_t)l*H_,
            ew1l+(size_t)512*H_, ew1l+(size_t)513*H_, e_b1+(size_t)l*H_,
            WfU + (size_t)l*131072, WfM + (size_t)l*131072,
            x_b2+(size_t)l*H_, x_w3+(size_t)l*H_,
            e_b2+(size_t)l*H_, att_w+(size_t)l*H_, att_b+l,
            x_new, agg);

        // hm1 = silu(agg @ hw1_bot + h_b1 + Htop)  (fp32, R12 path)
        GArgs ha = {};
        ha.g[0] = { agg, hw1l+(size_t)256*H_, h_b1+(size_t)l*H_, Htop, nullptr, hm1 };
        k_gemm64<1><<<dim3(BN_/64,H_/64,1),256,0,stream>>>(ha, BN_, H_);

        // h = (hm1 @ hw2 + h_b2 + h) * nmask  (fp32, R12 path)
        GArgs h2 = {};
        h2.g[0] = { hm1, h_w2+(size_t)l*H_*H_, h_b2+(size_t)l*H_, h, nmask, h };
        k_gemm64<0><<<dim3(BN_/64,H_/64,1),256,0,stream>>>(h2, BN_, H_);

        float* tmp = x_cur; x_cur = x_new; x_new = tmp;
    }

    k_out_x<<<B_,64,0,stream>>>(x_cur, x_in, nmask, out);
    k_out_h<<<BN_,64,0,stream>>>(h, wout_w, wout_b, nmask, out);
}